// Round 6
// baseline (169.033 us; speedup 1.0000x reference)
//
#include <hip/hip_runtime.h>
#include <math.h>

// Problem constants (reference: B=4, N=2048, TIMESTEPS=1000, speed=0.01)
#define TIMESTEPS 1000
constexpr int Bc = 4;
constexpr int Nc = 2048;
constexpr int EcI = Nc * (Nc - 1) / 2;   // 2,096,128

typedef float fvec4 __attribute__((ext_vector_type(4)));
// 4-byte-aligned float4: gfx9+ global loads support dword-aligned dwordx4.
struct __attribute__((packed, aligned(4))) f4u { fvec4 v; };

__device__ __forceinline__ float elem_loss(int a0, float uu, float qv,
    float p0, float p1, float qt00, float qt01, float qt10, float qt11)
{
    float ps  = a0 ? p1 : p0;
    bool  x   = (uu < ps);
    float t0  = x ? qt01 : qt00;
    float t1  = x ? qt11 : qt10;
    float qtv = a0 ? t1 : t0;
    return fmaxf(qv, 0.0f) - qv * qtv + __logf(1.0f + __expf(-fabsf(qv)));
}

// Block = one (batch, virtual-row-pair): rows iA=r (len r) and iB=2047-r
// (len 2047-r). Rows split into 4-wide groups; GA+GB in {512,513}.
// Thread handles groups g=tid and g=tid+256 (always valid since GT>=512);
// thread 0 picks up group 512 when GT==513. All adj/u loads are 16B-aligned
// vec4; q is a 4B-aligned dwordx4. Full groups never cross their row end.
__global__ __launch_bounds__(256) void diff_loss_kernel(
    const int* __restrict__ adj, const int* __restrict__ t,
    const float* __restrict__ u, const float* __restrict__ q,
    double* __restrict__ partials)
{
    __shared__ float tab[Bc][8];
    if (threadIdx.x < Bc) {
        int b = threadIdx.x;
        int tb = t[b];
        // Qt[k] built with ts=k+1: flip = 0.5*(1 - 0.98^(k+1))
        float f_t = 0.5f * (1.0f - powf(0.98f, (float)(tb + 1)));
        int tpe = (tb == 0) ? TIMESTEPS : tb;        // Qt[t-1], wrap -1 -> 999
        float f_p = 0.5f * (1.0f - powf(0.98f, (float)tpe));
        float f0  = 0.5f * (1.0f - 0.98f);           // Qt[0] flip
        float omf_t = 1.0f - f_t;
        tab[b][0] = f_t;        // probs1 when a0==0
        tab[b][1] = omf_t;      // probs1 when a0==1
        // q_target(a0,x) = lik1(x)*pri1(a0)/evid(a0,x); evid=(x==a0)?1-f_t:f_t
        tab[b][2] = f0          * f_p          / omf_t;  // a0=0,x=0
        tab[b][3] = (1.0f - f0) * f_p          / f_t;    // a0=0,x=1
        tab[b][4] = f0          * (1.0f - f_p) / f_t;    // a0=1,x=0
        tab[b][5] = (1.0f - f0) * (1.0f - f_p) / omf_t;  // a0=1,x=1
    }
    __syncthreads();

    const int bid = blockIdx.x;                 // [0, 4096)
    const int b = bid >> 10;
    const int r = bid & 1023;
    const int lenA = r;                         // row iA = r
    const int lenB = (Nc - 1) - r;              // row iB = 2047 - r
    const int GA = (lenA + 3) >> 2;
    const int GB = (lenB + 3) >> 2;
    const int GT = GA + GB;                     // 512 or 513
    const int mA = (b << 22) + (lenA << 11);    // adj/u row bases (i == len)
    const int mB = (b << 22) + (lenB << 11);
    const int eA = b * EcI + ((lenA * (lenA - 1)) >> 1);   // q row bases
    const int eB = b * EcI + ((lenB * (lenB - 1)) >> 1);

    const float p0   = tab[b][0], p1   = tab[b][1];
    const float qt00 = tab[b][2], qt01 = tab[b][3];
    const float qt10 = tab[b][4], qt11 = tab[b][5];

    const int tid = threadIdx.x;
    // decode both groups
    const int g0 = tid, g1 = tid + 256;
    const bool inA0 = g0 < GA;
    const int  j00  = (inA0 ? g0 : g0 - GA) << 2;
    const int  m0   = (inA0 ? mA : mB) + j00;
    const int  e0   = (inA0 ? eA : eB) + j00;
    const int  rem0 = (inA0 ? lenA : lenB) - j00;    // >= 1
    const bool inA1 = g1 < GA;
    const int  j01  = (inA1 ? g1 : g1 - GA) << 2;
    const int  m1   = (inA1 ? mA : mB) + j01;
    const int  e1   = (inA1 ? eA : eB) + j01;
    const int  rem1 = (inA1 ? lenA : lenB) - j01;    // >= 1

    // issue all wide loads up front
    const int4  a40 = *(const int4*)(adj + m0);
    const fvec4 u40 = *(const fvec4*)(u + m0);
    const int4  a41 = *(const int4*)(adj + m1);
    const fvec4 u41 = *(const fvec4*)(u + m1);

    fvec4 q40, q41;
    if (rem0 >= 4) {
        q40 = ((const f4u*)(q + e0))->v;       // 4B-aligned dwordx4
    } else {                                    // rare row-tail (<=2/block)
        int c1 = rem0 > 1 ? 1 : 0, c2 = rem0 > 2 ? 2 : 0;
        q40 = (fvec4){q[e0], q[e0 + c1], q[e0 + c2], q[e0]};
    }
    if (rem1 >= 4) {
        q41 = ((const f4u*)(q + e1))->v;
    } else {
        int c1 = rem1 > 1 ? 1 : 0, c2 = rem1 > 2 ? 2 : 0;
        q41 = (fvec4){q[e1], q[e1 + c1], q[e1 + c2], q[e1]};
    }

    float sum = 0.0f;
    {
        float l0 = elem_loss(a40.x, u40.x, q40.x, p0,p1,qt00,qt01,qt10,qt11);
        float l1 = elem_loss(a40.y, u40.y, q40.y, p0,p1,qt00,qt01,qt10,qt11);
        float l2 = elem_loss(a40.z, u40.z, q40.z, p0,p1,qt00,qt01,qt10,qt11);
        float l3 = elem_loss(a40.w, u40.w, q40.w, p0,p1,qt00,qt01,qt10,qt11);
        sum += l0;                              // rem0 >= 1 always
        sum += (rem0 > 1) ? l1 : 0.0f;
        sum += (rem0 > 2) ? l2 : 0.0f;
        sum += (rem0 > 3) ? l3 : 0.0f;
    }
    {
        float l0 = elem_loss(a41.x, u41.x, q41.x, p0,p1,qt00,qt01,qt10,qt11);
        float l1 = elem_loss(a41.y, u41.y, q41.y, p0,p1,qt00,qt01,qt10,qt11);
        float l2 = elem_loss(a41.z, u41.z, q41.z, p0,p1,qt00,qt01,qt10,qt11);
        float l3 = elem_loss(a41.w, u41.w, q41.w, p0,p1,qt00,qt01,qt10,qt11);
        sum += l0;                              // rem1 >= 1 always
        sum += (rem1 > 1) ? l1 : 0.0f;
        sum += (rem1 > 2) ? l2 : 0.0f;
        sum += (rem1 > 3) ? l3 : 0.0f;
    }
    // leftover group 512 when GT == 513 (row B tail; rem in {1,2})
    if ((GT == 513) && (tid == 0)) {
        int j0 = (512 - GA) << 2;
        int m = mB + j0, e = eB + j0, rem = lenB - j0;
        for (int k = 0; k < rem; ++k)
            sum += elem_loss(adj[m + k], u[m + k], q[e + k],
                             p0,p1,qt00,qt01,qt10,qt11);
    }

    double acc = (double)sum;
    // wave (64) shuffle reduce, then cross-wave via LDS
    for (int off = 32; off > 0; off >>= 1)
        acc += __shfl_down(acc, off, 64);
    __shared__ double wsum[4];
    int lane = threadIdx.x & 63, wid = threadIdx.x >> 6;
    if (lane == 0) wsum[wid] = acc;
    __syncthreads();
    if (threadIdx.x == 0)
        partials[blockIdx.x] = wsum[0] + wsum[1] + wsum[2] + wsum[3];
}

// Reduce per-block partials, write mean as f32.
__global__ __launch_bounds__(256) void final_reduce_kernel(
    const double* __restrict__ partials, int nb, float* __restrict__ out)
{
    double acc = 0.0;
    for (int idx = threadIdx.x; idx < nb; idx += blockDim.x)
        acc += partials[idx];
    for (int off = 32; off > 0; off >>= 1)
        acc += __shfl_down(acc, off, 64);
    __shared__ double wsum[4];
    int lane = threadIdx.x & 63, wid = threadIdx.x >> 6;
    if (lane == 0) wsum[wid] = acc;
    __syncthreads();
    if (threadIdx.x == 0)
        out[0] = (float)((wsum[0] + wsum[1] + wsum[2] + wsum[3]) /
                         ((double)Bc * (double)EcI));
}

extern "C" void kernel_launch(void* const* d_in, const int* in_sizes, int n_in,
                              void* d_out, int out_size, void* d_ws, size_t ws_size,
                              hipStream_t stream) {
    const int*   adj = (const int*)d_in[0];   // adj_start (B,N,N) int32
    const int*   t   = (const int*)d_in[1];   // t (B,) int32
    const float* u   = (const float*)d_in[2]; // u (B,N,N) f32
    const float* q   = (const float*)d_in[3]; // q_approx (B,E) f32
    float*  out      = (float*)d_out;
    double* partials = (double*)d_ws;         // 4096 doubles (32 KB)

    const int NB = Bc * 1024;                 // 4096 blocks, exact cover
    diff_loss_kernel<<<NB, 256, 0, stream>>>(adj, t, u, q, partials);
    final_reduce_kernel<<<1, 256, 0, stream>>>(partials, NB, out);
}

// Round 7
// 166.457 us; speedup vs baseline: 1.0155x; 1.0155x over previous
//
#include <hip/hip_runtime.h>
#include <math.h>

// Problem constants (reference: B=4, N=2048, TIMESTEPS=1000, speed=0.01)
#define TIMESTEPS 1000
constexpr int Bc = 4;
constexpr int Nc = 2048;
constexpr int EcI = Nc * (Nc - 1) / 2;   // 2,096,128

typedef const __attribute__((address_space(1))) void gv_t;
typedef __attribute__((address_space(3))) void lv_t;
#define DMA4(gp, lp) __builtin_amdgcn_global_load_lds((gv_t*)(gp), (lv_t*)(lp), 4, 0, 0)

// Block = one (batch, virtual-row-pair): rows iA=r (len r), iB=2047-r
// (len 2047-r); 2047 elements total in slot space s:
//   s < lenA -> (iA, s);  else -> (iB, s - lenA).
// ALL loads are async DMA global->LDS (width 4, per-lane gather on the global
// side, lane-consecutive slots on the LDS side). No register round-trip, no
// compiler-serialized waitcnt: 24 outstanding DMAs per wave, drained once at
// the barrier. Compute reads LDS as aligned b128 in unified slot space.
__global__ __launch_bounds__(256) void diff_loss_kernel(
    const int* __restrict__ adj, const int* __restrict__ t,
    const float* __restrict__ u, const float* __restrict__ q,
    double* __restrict__ partials)
{
    __shared__ int   adjL[2048];
    __shared__ float uL[2048];
    __shared__ float qL[2048];
    __shared__ float tab[Bc][8];
    __shared__ double wsum[4];

    const int tid = threadIdx.x;
    const int bid = blockIdx.x;                 // [0, 4096)
    const int b = bid >> 10;
    const int r = bid & 1023;
    const int lenA = r;                         // row iA = r
    const int iB   = (Nc - 1) - r;              // row B, length iB
    const int mA = (b << 22) + (lenA << 11);    // adj/u row bases
    const int mB = (b << 22) + (iB << 11);
    const int eA = b * EcI + ((lenA * (lenA - 1)) >> 1);   // q row bases
    const int eB = b * EcI + ((iB * (iB - 1)) >> 1);

    // start the t[b] load early (tab built after DMA issue, before barrier)
    int tb = (tid < Bc) ? t[tid] : 0;

    // ---- issue all DMA (24 per thread), no waits ----
    #pragma unroll
    for (int k = 0; k < 8; ++k) {
        int s = tid + (k << 8);
        if (s < Nc - 1) {
            bool inA = (s < lenA);
            int m = inA ? (mA + s) : (mB + (s - lenA));
            int e = inA ? (eA + s) : (eB + (s - lenA));
            DMA4(adj + m, &adjL[s]);
            DMA4(u   + m, &uL[s]);
            DMA4(q   + e, &qL[s]);
        }
    }

    // ---- build the 4-value q_target table while DMAs fly ----
    if (tid < Bc) {
        // Qt[k] built with ts=k+1: flip = 0.5*(1 - 0.98^(k+1))
        float f_t = 0.5f * (1.0f - powf(0.98f, (float)(tb + 1)));
        int tpe = (tb == 0) ? TIMESTEPS : tb;        // Qt[t-1], wrap -1 -> 999
        float f_p = 0.5f * (1.0f - powf(0.98f, (float)tpe));
        float f0  = 0.5f * (1.0f - 0.98f);           // Qt[0] flip
        float omf_t = 1.0f - f_t;
        tab[tid][0] = f_t;        // probs1 when a0==0
        tab[tid][1] = omf_t;      // probs1 when a0==1
        // q_target(a0,x) = lik1(x)*pri1(a0)/evid(a0,x); evid=(x==a0)?1-f_t:f_t
        tab[tid][2] = f0          * f_p          / omf_t;  // a0=0,x=0
        tab[tid][3] = (1.0f - f0) * f_p          / f_t;    // a0=0,x=1
        tab[tid][4] = f0          * (1.0f - f_p) / f_t;    // a0=1,x=0
        tab[tid][5] = (1.0f - f0) * (1.0f - f_p) / omf_t;  // a0=1,x=1
    }

    __syncthreads();   // drains vmcnt(0): all DMAs landed; tab visible

    const float p0   = tab[b & 0][0], p1 = tab[0][1];   // placeholder, fixed below
    // (read the real batch row; b is block-uniform)
    const float P0   = tab[b][0], P1   = tab[b][1];
    const float qt00 = tab[b][2], qt01 = tab[b][3];
    const float qt10 = tab[b][4], qt11 = tab[b][5];
    (void)p0; (void)p1;

    float sum = 0.0f;
    #pragma unroll
    for (int g = 0; g < 2; ++g) {
        int s0 = (tid << 2) + (g << 10);            // 16B-aligned slot group
        const int4   a4 = *(const int4*)&adjL[s0];
        const float4 u4 = *(const float4*)&uL[s0];
        const float4 q4 = *(const float4*)&qL[s0];
        const int   aa[4] = {a4.x, a4.y, a4.z, a4.w};
        const float uu[4] = {u4.x, u4.y, u4.z, u4.w};
        const float qq[4] = {q4.x, q4.y, q4.z, q4.w};
        #pragma unroll
        for (int k = 0; k < 4; ++k) {
            bool valid = (s0 + k) < (Nc - 1);       // only slot 2047 invalid
            int   a0 = aa[k];
            float ps  = a0 ? P1 : P0;
            bool  x   = (uu[k] < ps);
            float t0  = x ? qt01 : qt00;
            float t1  = x ? qt11 : qt10;
            float qtv = a0 ? t1 : t0;
            float qv  = qq[k];
            float l = fmaxf(qv, 0.0f) - qv * qtv
                    + __logf(1.0f + __expf(-fabsf(qv)));
            sum += valid ? l : 0.0f;
        }
    }

    double acc = (double)sum;
    // wave (64) shuffle reduce, then cross-wave via LDS
    for (int off = 32; off > 0; off >>= 1)
        acc += __shfl_down(acc, off, 64);
    int lane = tid & 63, wid = tid >> 6;
    if (lane == 0) wsum[wid] = acc;
    __syncthreads();
    if (tid == 0)
        partials[blockIdx.x] = wsum[0] + wsum[1] + wsum[2] + wsum[3];
}

// Reduce per-block partials, write mean as f32.
__global__ __launch_bounds__(256) void final_reduce_kernel(
    const double* __restrict__ partials, int nb, float* __restrict__ out)
{
    double acc = 0.0;
    for (int idx = threadIdx.x; idx < nb; idx += blockDim.x)
        acc += partials[idx];
    for (int off = 32; off > 0; off >>= 1)
        acc += __shfl_down(acc, off, 64);
    __shared__ double wsum[4];
    int lane = threadIdx.x & 63, wid = threadIdx.x >> 6;
    if (lane == 0) wsum[wid] = acc;
    __syncthreads();
    if (threadIdx.x == 0)
        out[0] = (float)((wsum[0] + wsum[1] + wsum[2] + wsum[3]) /
                         ((double)Bc * (double)EcI));
}

extern "C" void kernel_launch(void* const* d_in, const int* in_sizes, int n_in,
                              void* d_out, int out_size, void* d_ws, size_t ws_size,
                              hipStream_t stream) {
    const int*   adj = (const int*)d_in[0];   // adj_start (B,N,N) int32
    const int*   t   = (const int*)d_in[1];   // t (B,) int32
    const float* u   = (const float*)d_in[2]; // u (B,N,N) f32
    const float* q   = (const float*)d_in[3]; // q_approx (B,E) f32
    float*  out      = (float*)d_out;
    double* partials = (double*)d_ws;         // 4096 doubles (32 KB)

    const int NB = Bc * 1024;                 // 4096 blocks, exact cover
    diff_loss_kernel<<<NB, 256, 0, stream>>>(adj, t, u, q, partials);
    final_reduce_kernel<<<1, 256, 0, stream>>>(partials, NB, out);
}